// Round 15
// baseline (846.630 us; speedup 1.0000x reference)
//
#include <hip/hip_runtime.h>
#include <math.h>

#define RC (-4.3711388e-08f)   // cosf(float32(pi/2))
#define RS (1.0f)              // sinf(float32(pi/2))
#define STAT_BLOCKS 240
#define SCAN_BS 1024
#define NCH 256                // partition chunks
#define NR 8                   // dst regions
#define NSC 32                 // subchunks per region (hist/fill)
#define RN_MAX 12512           // max bins per region (N <= 100096)

typedef unsigned int u32;
typedef unsigned short u16;
typedef float v2f __attribute__((ext_vector_type(2)));

// NOTE (R13 post-mortem): nt STORES regressed 2x — producer->consumer reuse
// through L2 is load-bearing. Plain stores only. nt LOADS on read-once streams
// (fill2/hist2 bucket scans) are the correct use: keep scatter lines resident.
__device__ __forceinline__ void nts(float4* p, float4 v) { *p = v; }
__device__ __forceinline__ void nts(uint4* p, uint4 v) { *p = v; }
__device__ __forceinline__ int ntl(const int* p) {
    return __builtin_nontemporal_load(p);
}

__device__ __forceinline__ u16 f2bf(float f) {
    u32 u = __float_as_uint(f);
    u += 0x7FFFu + ((u >> 16) & 1u);
    return (u16)(u >> 16);
}
__device__ __forceinline__ u32 pack2(float lo, float hi) {
    return (u32)f2bf(lo) | ((u32)f2bf(hi) << 16);
}
__device__ __forceinline__ float bfl(u32 u) { return __uint_as_float(u << 16); }
__device__ __forceinline__ float bfh(u32 u) { return __uint_as_float(u & 0xFFFF0000u); }

__device__ __forceinline__ u32 pack4fp8(float a, float b, float c, float d) {
    int v = 0;
    v = __builtin_amdgcn_cvt_pk_fp8_f32(a, b, v, false);
    v = __builtin_amdgcn_cvt_pk_fp8_f32(c, d, v, true);
    return (u32)v;
}

// ---------------- normalize ----------------
__global__ void stats_partial_kernel(const float* __restrict__ x,
                                     float* __restrict__ part, int n) {
    float s0 = 0.f, s1 = 0.f, sr0 = 0.f, sr1 = 0.f;
    float mx0 = -1e30f, mn0 = 1e30f, mx1 = -1e30f, mn1 = 1e30f;
    float mxr0 = -1e30f, mxr1 = -1e30f, mxA = -1e30f;
    for (int i = blockIdx.x * blockDim.x + threadIdx.x; i < n;
         i += gridDim.x * blockDim.x) {
        float c0 = x[i * 3 + 0], c1 = x[i * 3 + 1], a = x[i * 3 + 2];
        float r0 = RC * c0 - RS * c1;
        float r1 = RS * c0 + RC * c1;
        s0 += c0; s1 += c1; sr0 += r0; sr1 += r1;
        mx0 = fmaxf(mx0, c0); mn0 = fminf(mn0, c0);
        mx1 = fmaxf(mx1, c1); mn1 = fminf(mn1, c1);
        mxr0 = fmaxf(mxr0, r0); mxr1 = fmaxf(mxr1, r1);
        mxA = fmaxf(mxA, a);
    }
    #pragma unroll
    for (int off = 32; off > 0; off >>= 1) {
        s0 += __shfl_down(s0, off);
        s1 += __shfl_down(s1, off);
        sr0 += __shfl_down(sr0, off);
        sr1 += __shfl_down(sr1, off);
        mx0 = fmaxf(mx0, __shfl_down(mx0, off));
        mn0 = fminf(mn0, __shfl_down(mn0, off));
        mx1 = fmaxf(mx1, __shfl_down(mx1, off));
        mn1 = fminf(mn1, __shfl_down(mn1, off));
        mxr0 = fmaxf(mxr0, __shfl_down(mxr0, off));
        mxr1 = fmaxf(mxr1, __shfl_down(mxr1, off));
        mxA = fmaxf(mxA, __shfl_down(mxA, off));
    }
    __shared__ float sh[11][4];
    int wid = threadIdx.x >> 6, lane = threadIdx.x & 63;
    if (lane == 0) {
        sh[0][wid] = s0; sh[1][wid] = s1; sh[2][wid] = sr0; sh[3][wid] = sr1;
        sh[4][wid] = mx0; sh[5][wid] = mn0; sh[6][wid] = mx1; sh[7][wid] = mn1;
        sh[8][wid] = mxr0; sh[9][wid] = mxr1; sh[10][wid] = mxA;
    }
    __syncthreads();
    if (threadIdx.x == 0) {
        float v[11];
        #pragma unroll
        for (int k = 0; k < 4; ++k) v[k] = sh[k][0] + sh[k][1] + sh[k][2] + sh[k][3];
        v[4] = fmaxf(fmaxf(sh[4][0], sh[4][1]), fmaxf(sh[4][2], sh[4][3]));
        v[5] = fminf(fminf(sh[5][0], sh[5][1]), fminf(sh[5][2], sh[5][3]));
        v[6] = fmaxf(fmaxf(sh[6][0], sh[6][1]), fmaxf(sh[6][2], sh[6][3]));
        v[7] = fminf(fminf(sh[7][0], sh[7][1]), fminf(sh[7][2], sh[7][3]));
        #pragma unroll
        for (int k = 8; k < 11; ++k)
            v[k] = fmaxf(fmaxf(sh[k][0], sh[k][1]), fmaxf(sh[k][2], sh[k][3]));
        #pragma unroll
        for (int k = 0; k < 11; ++k) part[k * STAT_BLOCKS + blockIdx.x] = v[k];
    }
}

__global__ void stats_final_kernel(const float* __restrict__ part,
                                   float* __restrict__ stats, int n) {
    __shared__ float red[11];
    int t = threadIdx.x;
    if (t < 11) {
        float v;
        if (t < 4) {
            v = 0.f;
            for (int b = 0; b < STAT_BLOCKS; ++b) v += part[t * STAT_BLOCKS + b];
        } else if (t == 5 || t == 7) {
            v = 1e30f;
            for (int b = 0; b < STAT_BLOCKS; ++b) v = fminf(v, part[t * STAT_BLOCKS + b]);
        } else {
            v = -1e30f;
            for (int b = 0; b < STAT_BLOCKS; ++b) v = fmaxf(v, part[t * STAT_BLOCKS + b]);
        }
        red[t] = v;
    }
    __syncthreads();
    if (t == 0) {
        float range0 = red[4] - red[5];
        float range1 = red[6] - red[7];
        bool rot = range1 > range0;
        stats[0] = rot ? 1.f : 0.f;
        stats[1] = (rot ? red[2] : red[0]) / (float)n;
        stats[2] = (rot ? red[3] : red[1]) / (float)n;
        stats[3] = rot ? red[8] : red[4];
        stats[4] = rot ? red[9] : red[6];
        stats[5] = red[10];
    }
}

__global__ void normalize_kernel(const float* __restrict__ x,
                                 const float* __restrict__ stats,
                                 float* __restrict__ h0, int n) {
    int i = blockIdx.x * blockDim.x + threadIdx.x;
    if (i >= n) return;
    float c0 = x[i * 3 + 0], c1 = x[i * 3 + 1], a = x[i * 3 + 2];
    if (stats[0] != 0.f) {
        float r0 = RC * c0 - RS * c1;
        float r1 = RS * c0 + RC * c1;
        c0 = r0; c1 = r1;
    }
    h0[i * 3 + 0] = (c0 - stats[1]) / stats[3];
    h0[i * 3 + 1] = (c1 - stats[2]) / stats[4];
    h0[i * 3 + 2] = a / stats[5];
}

// ---------------- CSR build: radix-partition + LDS histogram ----------------
__global__ void cnt_kernel(const int* __restrict__ dst, int* __restrict__ counts,
                           int e, int ech, int rn) {
    int c = blockIdx.x;
    int cnt[NR];
    #pragma unroll
    for (int k = 0; k < NR; ++k) cnt[k] = 0;
    int start = c * ech, end = min(start + ech, e);
    for (int i = start + threadIdx.x; i < end; i += blockDim.x) {
        int r = dst[i] / rn;
        #pragma unroll
        for (int k = 0; k < NR; ++k) cnt[k] += (r == k) ? 1 : 0;
    }
    __shared__ int sh[NR];
    if (threadIdx.x < NR) sh[threadIdx.x] = 0;
    __syncthreads();
    #pragma unroll
    for (int k = 0; k < NR; ++k)
        if (cnt[k]) atomicAdd(&sh[k], cnt[k]);
    __syncthreads();
    if (threadIdx.x < NR) counts[c * NR + threadIdx.x] = sh[threadIdx.x];
}

__global__ void boff_kernel(const int* __restrict__ counts, int* __restrict__ gof,
                            int* __restrict__ bb) {
    __shared__ int sbb[NR + 1];
    __shared__ int rt[NR];
    int t = threadIdx.x;
    if (t < NR) {
        int run = 0;
        for (int c = 0; c < NCH; ++c) {
            gof[c * NR + t] = run;
            run += counts[c * NR + t];
        }
        rt[t] = run;
    }
    __syncthreads();
    if (t == 0) {
        int b = 0;
        for (int r = 0; r < NR; ++r) { sbb[r] = b; b += rt[r]; }
        sbb[NR] = b;
        for (int r = 0; r <= NR; ++r) bb[r] = sbb[r];
    }
    __syncthreads();
    if (t < NR) {
        int b = sbb[t];
        for (int c = 0; c < NCH; ++c) gof[c * NR + t] += b;
    }
}

__global__ void scatter_kernel(const int* __restrict__ src, const int* __restrict__ dst,
                               const int* __restrict__ gof,
                               int* __restrict__ bdst, int* __restrict__ bsrc,
                               int e, int ech, int rn) {
    __shared__ int cur[NR];
    int c = blockIdx.x;
    if (threadIdx.x < NR) cur[threadIdx.x] = gof[c * NR + threadIdx.x];
    __syncthreads();
    int start = c * ech, end = min(start + ech, e);
    for (int i = start + threadIdx.x; i < end; i += blockDim.x) {
        int d = dst[i];
        int s = src[i];
        int r = d / rn;
        int p = atomicAdd(&cur[r], 1);
        bdst[p] = d;
        bsrc[p] = s;
    }
}

__global__ void hist2_kernel(const int* __restrict__ bdst, const int* __restrict__ bb,
                             int* __restrict__ part_hist, int rn, int n) {
    __shared__ int hist[RN_MAX];
    int r = blockIdx.x & (NR - 1);
    int sc = blockIdx.x >> 3;
    int lo = bb[r], hi = bb[r + 1];
    int clen = (hi - lo + NSC - 1) / NSC;
    int start = lo + sc * clen, end = min(start + clen, hi);
    int base = r * rn;
    int cnt = min(rn, n - base);
    if (cnt <= 0) return;
    for (int t = threadIdx.x; t < cnt; t += blockDim.x) hist[t] = 0;
    __syncthreads();
    for (int i = start + threadIdx.x; i < end; i += blockDim.x)
        atomicAdd(&hist[ntl(bdst + i) - base], 1);
    __syncthreads();
    int* outp = part_hist + ((size_t)(r * NSC + sc)) * rn;
    for (int t = threadIdx.x; t < cnt; t += blockDim.x) outp[t] = hist[t];
}

__global__ void prefix2_kernel(int* __restrict__ part_hist, int* __restrict__ deg,
                               int rn, int n) {
    int node = blockIdx.x * blockDim.x + threadIdx.x;
    if (node >= n) return;
    int r = node / rn, lb = node - r * rn;
    int* p = part_hist + ((size_t)(r * NSC)) * rn + lb;
    int run = 0;
    #pragma unroll 4
    for (int sc = 0; sc < NSC; ++sc) {
        int v = p[(size_t)sc * rn];
        p[(size_t)sc * rn] = run;
        run += v;
    }
    deg[node] = run;
}

__global__ void fill2_kernel(const int* __restrict__ bdst, const int* __restrict__ bsrc,
                             const int* __restrict__ bb, const int* __restrict__ row_ptr,
                             const int* __restrict__ part_hist, int* __restrict__ csr_src,
                             int rn, int n) {
    __shared__ int hist[RN_MAX];
    int r = blockIdx.x & (NR - 1);
    int sc = blockIdx.x >> 3;
    int lo = bb[r], hi = bb[r + 1];
    int clen = (hi - lo + NSC - 1) / NSC;
    int start = lo + sc * clen, end = min(start + clen, hi);
    int base = r * rn;
    int cnt = min(rn, n - base);
    if (cnt <= 0) return;
    for (int t = threadIdx.x; t < cnt; t += blockDim.x) hist[t] = 0;
    __syncthreads();
    const int* pref = part_hist + ((size_t)(r * NSC + sc)) * rn;
    for (int i = start + threadIdx.x; i < end; i += blockDim.x) {
        int d = ntl(bdst + i);
        int s = ntl(bsrc + i);
        int lb = d - base;
        int lr = atomicAdd(&hist[lb], 1);
        csr_src[row_ptr[d] + pref[lb] + lr] = s;
    }
}

__global__ void scanA_kernel(const int* __restrict__ deg, int* __restrict__ bsum, int n) {
    __shared__ int sh[256];
    int b = blockIdx.x, t = threadIdx.x;
    int base = b * SCAN_BS + t * 4;
    int s = 0;
    if (base + 3 < n) {
        int4 v = *(const int4*)(deg + base);
        s = v.x + v.y + v.z + v.w;
    } else {
        for (int k = 0; k < 4; ++k) if (base + k < n) s += deg[base + k];
    }
    sh[t] = s; __syncthreads();
    for (int o = 128; o > 0; o >>= 1) {
        if (t < o) sh[t] += sh[t + o];
        __syncthreads();
    }
    if (t == 0) bsum[b] = sh[0];
}

__global__ void scanB_kernel(const int* __restrict__ bsum, int* __restrict__ bscan,
                             int* __restrict__ row_ptr_n, int nb) {
    __shared__ int sh[1024];
    int t = threadIdx.x;
    int v = (t < nb) ? bsum[t] : 0;
    sh[t] = v; __syncthreads();
    for (int o = 1; o < 1024; o <<= 1) {
        int u = (t >= o) ? sh[t - o] : 0;
        __syncthreads();
        sh[t] += u;
        __syncthreads();
    }
    if (t < nb) bscan[t] = sh[t] - v;
    if (t == nb - 1) row_ptr_n[0] = sh[t];
}

__global__ void scanC_kernel(const int* __restrict__ deg, const int* __restrict__ bscan,
                             int* __restrict__ row_ptr, int n) {
    __shared__ int sh[256];
    int b = blockIdx.x, t = threadIdx.x;
    int base = b * SCAN_BS + t * 4;
    int v0 = 0, v1 = 0, v2 = 0, v3 = 0;
    if (base + 3 < n) {
        int4 v = *(const int4*)(deg + base);
        v0 = v.x; v1 = v.y; v2 = v.z; v3 = v.w;
    } else {
        if (base < n) v0 = deg[base];
        if (base + 1 < n) v1 = deg[base + 1];
        if (base + 2 < n) v2 = deg[base + 2];
        if (base + 3 < n) v3 = deg[base + 3];
    }
    int s = v0 + v1 + v2 + v3;
    sh[t] = s; __syncthreads();
    for (int o = 1; o < 256; o <<= 1) {
        int u = (t >= o) ? sh[t - o] : 0;
        __syncthreads();
        sh[t] += u;
        __syncthreads();
    }
    int ex = sh[t] - s + bscan[b];
    if (base < n)     row_ptr[base] = ex;
    if (base + 1 < n) row_ptr[base + 1] = ex + v0;
    if (base + 2 < n) row_ptr[base + 2] = ex + v0 + v1;
    if (base + 3 < n) row_ptr[base + 3] = ex + v0 + v1 + v2;
}

// ---------------- cast f32 -> bf16 (8 elems/thread) ----------------
__global__ void cast_bf16_kernel(const float* __restrict__ xin,
                                 u16* __restrict__ xb, int n8) {
    int i = blockIdx.x * blockDim.x + threadIdx.x;
    if (i >= n8) return;
    const float4* a = (const float4*)xin + (size_t)i * 2;
    float4 v0 = a[0], v1 = a[1];
    uint4 q;
    q.x = pack2(v0.x, v0.y); q.y = pack2(v0.z, v0.w);
    q.z = pack2(v1.x, v1.y); q.w = pack2(v1.z, v1.w);
    nts((uint4*)xb + i, q);
}

// ---------------- premultiply: y = x @ wl, output bf16 ----------------
template <int FIN, int FOUT>
__global__ __launch_bounds__(256, 4)
void premult_kernel(const float* __restrict__ xin,
                    const float* __restrict__ wl,
                    u16* __restrict__ y, int n) {
    __shared__ float4 s_w[FIN * FOUT / 4];
    for (int t = threadIdx.x; t < FIN * FOUT / 4; t += blockDim.x)
        s_w[t] = ((const float4*)wl)[t];
    __syncthreads();
    int i = blockIdx.x * blockDim.x + threadIdx.x;
    if (i >= n) return;
    float4 acc[FOUT / 4];
    #pragma unroll
    for (int oc = 0; oc < FOUT / 4; ++oc) acc[oc] = make_float4(0.f, 0.f, 0.f, 0.f);
    const float4* x4 = (const float4*)xin + (size_t)i * (FIN / 4);
    #pragma unroll 2
    for (int fc = 0; fc < FIN / 4; ++fc) {
        float4 xv = x4[fc];
        #pragma unroll
        for (int c = 0; c < 4; ++c) {
            float xf = c == 0 ? xv.x : c == 1 ? xv.y : c == 2 ? xv.z : xv.w;
            int f = fc * 4 + c;
            #pragma unroll
            for (int oc = 0; oc < FOUT / 4; ++oc) {
                float4 w = s_w[f * (FOUT / 4) + oc];
                acc[oc].x += xf * w.x; acc[oc].y += xf * w.y;
                acc[oc].z += xf * w.z; acc[oc].w += xf * w.w;
            }
        }
    }
    uint4* y4 = (uint4*)(y + (size_t)i * FOUT);
    #pragma unroll
    for (int g = 0; g < FOUT / 8; ++g) {
        uint4 q;
        q.x = pack2(acc[2 * g].x, acc[2 * g].y);
        q.y = pack2(acc[2 * g].z, acc[2 * g].w);
        q.z = pack2(acc[2 * g + 1].x, acc[2 * g + 1].y);
        q.w = pack2(acc[2 * g + 1].z, acc[2 * g + 1].w);
        nts(y4 + g, q);
    }
}

// ---------------- premultiply: y = x @ wl, output fp8 (output-tiled) ----------------
template <int FIN, int FOUT, int OTILE>
__global__ __launch_bounds__(256, 4)
void premult_fp8_kernel(const float* __restrict__ xin,
                        const float* __restrict__ wl,
                        u32* __restrict__ y, int n) {
    constexpr int OT4 = OTILE / 4;
    const int to = blockIdx.y * OTILE;
    __shared__ float4 s_w[FIN * OT4];
    for (int t = threadIdx.x; t < FIN * OT4; t += blockDim.x) {
        int f = t / OT4, j = t % OT4;
        s_w[t] = ((const float4*)(wl + f * FOUT + to))[j];
    }
    __syncthreads();
    int i = blockIdx.x * blockDim.x + threadIdx.x;
    if (i >= n) return;
    float4 acc[OT4];
    #pragma unroll
    for (int oc = 0; oc < OT4; ++oc) acc[oc] = make_float4(0.f, 0.f, 0.f, 0.f);
    const float4* x4 = (const float4*)xin + (size_t)i * (FIN / 4);
    #pragma unroll 2
    for (int fc = 0; fc < FIN / 4; ++fc) {
        float4 xv = x4[fc];
        #pragma unroll
        for (int c = 0; c < 4; ++c) {
            float xf = c == 0 ? xv.x : c == 1 ? xv.y : c == 2 ? xv.z : xv.w;
            int f = fc * 4 + c;
            #pragma unroll
            for (int oc = 0; oc < OT4; ++oc) {
                float4 w = s_w[f * OT4 + oc];
                acc[oc].x += xf * w.x; acc[oc].y += xf * w.y;
                acc[oc].z += xf * w.z; acc[oc].w += xf * w.w;
            }
        }
    }
    u32 w[OT4];
    #pragma unroll
    for (int oc = 0; oc < OT4; ++oc)
        w[oc] = pack4fp8(acc[oc].x, acc[oc].y, acc[oc].z, acc[oc].w);
    uint4* y4 = (uint4*)(y + (size_t)i * (FOUT / 4) + to / 4);
    #pragma unroll
    for (int g = 0; g < OT4 / 4; ++g) {
        uint4 q;
        q.x = w[4 * g + 0]; q.y = w[4 * g + 1];
        q.z = w[4 * g + 2]; q.w = w[4 * g + 3];
        nts(y4 + g, q);
    }
}

// ---------------- agg: mean of gathered bf16 rows -> f32 M (1 node/wave) ----------------
template <int F, int U>
__global__ void agg_bf16_kernel(const u16* __restrict__ xb,
                                float* __restrict__ M,
                                const int* __restrict__ row_ptr,
                                const int* __restrict__ csr_src, int n) {
    constexpr int LP = F / 8;
    constexpr int NPI = 64 / LP;
    int wid = threadIdx.x >> 6, lane = threadIdx.x & 63;
    int node = blockIdx.x * (blockDim.x >> 6) + wid;
    bool valid = node < n;
    int node_c = valid ? node : (n - 1);
    int rs = row_ptr[node_c];
    int deg = row_ptr[node_c + 1] - rs;
    int slot = lane / LP, chunk = lane % LP;
    const uint4* xb4 = (const uint4*)xb;

    float a0 = 0.f, a1 = 0.f, a2 = 0.f, a3 = 0.f, a4 = 0.f, a5 = 0.f, a6 = 0.f, a7 = 0.f;
    for (int base = 0; base < deg; base += U * NPI) {
        #pragma unroll
        for (int k = 0; k < U; ++k) {
            int nb = base + k * NPI + slot;
            bool v = nb < deg;
            int ia = v ? rs + nb : 0;
            int s = csr_src[ia];
            uint4 q = xb4[(size_t)s * LP + chunk];
            if (v) {
                a0 += bfl(q.x); a1 += bfh(q.x); a2 += bfl(q.y); a3 += bfh(q.y);
                a4 += bfl(q.z); a5 += bfh(q.z); a6 += bfl(q.w); a7 += bfh(q.w);
            }
        }
    }
    #pragma unroll
    for (int off = LP; off < 64; off <<= 1) {
        a0 += __shfl_xor(a0, off); a1 += __shfl_xor(a1, off);
        a2 += __shfl_xor(a2, off); a3 += __shfl_xor(a3, off);
        a4 += __shfl_xor(a4, off); a5 += __shfl_xor(a5, off);
        a6 += __shfl_xor(a6, off); a7 += __shfl_xor(a7, off);
    }
    float inv = 1.f / fmaxf((float)deg, 1.f);
    if (valid && lane < LP) {
        float4* Mp = (float4*)(M + (size_t)node * F + lane * 8);
        nts(Mp + 0, make_float4(a0 * inv, a1 * inv, a2 * inv, a3 * inv));
        nts(Mp + 1, make_float4(a4 * inv, a5 * inv, a6 * inv, a7 * inv));
    }
}

// ---------------- agg2: F=8 bf16, 2 nodes per wave (32-lane halves) ----------------
template <int U>
__global__ void agg2_bf16_kernel(const u16* __restrict__ xb,
                                 float* __restrict__ M,
                                 const int* __restrict__ row_ptr,
                                 const int* __restrict__ csr_src, int n) {
    int wid = threadIdx.x >> 6, lane = threadIdx.x & 63;
    int half = lane >> 5;
    int sl = lane & 31;
    int node = (blockIdx.x * (blockDim.x >> 6) + wid) * 2 + half;
    bool valid = node < n;
    int node_c = valid ? node : (n - 1);
    int rs = row_ptr[node_c];
    int deg = row_ptr[node_c + 1] - rs;
    const uint4* xb4 = (const uint4*)xb;

    float a0 = 0.f, a1 = 0.f, a2 = 0.f, a3 = 0.f, a4 = 0.f, a5 = 0.f, a6 = 0.f, a7 = 0.f;
    for (int base = 0; base < deg; base += U * 32) {
        #pragma unroll
        for (int k = 0; k < U; ++k) {
            int nb = base + k * 32 + sl;
            bool v = nb < deg;
            int ia = v ? rs + nb : 0;
            int s = csr_src[ia];
            uint4 q = xb4[s];
            if (v) {
                a0 += bfl(q.x); a1 += bfh(q.x); a2 += bfl(q.y); a3 += bfh(q.y);
                a4 += bfl(q.z); a5 += bfh(q.z); a6 += bfl(q.w); a7 += bfh(q.w);
            }
        }
    }
    #pragma unroll
    for (int off = 1; off < 32; off <<= 1) {
        a0 += __shfl_xor(a0, off); a1 += __shfl_xor(a1, off);
        a2 += __shfl_xor(a2, off); a3 += __shfl_xor(a3, off);
        a4 += __shfl_xor(a4, off); a5 += __shfl_xor(a5, off);
        a6 += __shfl_xor(a6, off); a7 += __shfl_xor(a7, off);
    }
    float inv = 1.f / fmaxf((float)deg, 1.f);
    if (valid && sl == 0) {
        float4* Mp = (float4*)(M + (size_t)node * 8);
        nts(Mp + 0, make_float4(a0 * inv, a1 * inv, a2 * inv, a3 * inv));
        nts(Mp + 1, make_float4(a4 * inv, a5 * inv, a6 * inv, a7 * inv));
    }
}

// ---------------- agg: mean of gathered fp8 rows -> f32 M ----------------
template <int F, int U>
__global__ void agg_fp8_kernel(const u32* __restrict__ xq,
                               float* __restrict__ M,
                               const int* __restrict__ row_ptr,
                               const int* __restrict__ csr_src, int n) {
    constexpr int LP = F / 8;
    constexpr int NPI = 64 / LP;
    int wid = threadIdx.x >> 6, lane = threadIdx.x & 63;
    int node = blockIdx.x * (blockDim.x >> 6) + wid;
    bool valid = node < n;
    int node_c = valid ? node : (n - 1);
    int rs = row_ptr[node_c];
    int deg = row_ptr[node_c + 1] - rs;
    int slot = lane / LP, chunk = lane % LP;
    const uint2* xq2 = (const uint2*)xq;

    float a0 = 0.f, a1 = 0.f, a2 = 0.f, a3 = 0.f, a4 = 0.f, a5 = 0.f, a6 = 0.f, a7 = 0.f;
    for (int base = 0; base < deg; base += U * NPI) {
        #pragma unroll
        for (int k = 0; k < U; ++k) {
            int nb = base + k * NPI + slot;
            bool v = nb < deg;
            int ia = v ? rs + nb : 0;
            int s = csr_src[ia];
            uint2 q = xq2[(size_t)s * LP + chunk];
            if (v) {
                v2f p0 = __builtin_amdgcn_cvt_pk_f32_fp8(q.x, false);
                v2f p1 = __builtin_amdgcn_cvt_pk_f32_fp8(q.x, true);
                v2f p2 = __builtin_amdgcn_cvt_pk_f32_fp8(q.y, false);
                v2f p3 = __builtin_amdgcn_cvt_pk_f32_fp8(q.y, true);
                a0 += p0.x; a1 += p0.y; a2 += p1.x; a3 += p1.y;
                a4 += p2.x; a5 += p2.y; a6 += p3.x; a7 += p3.y;
            }
        }
    }
    #pragma unroll
    for (int off = LP; off < 64; off <<= 1) {
        a0 += __shfl_xor(a0, off); a1 += __shfl_xor(a1, off);
        a2 += __shfl_xor(a2, off); a3 += __shfl_xor(a3, off);
        a4 += __shfl_xor(a4, off); a5 += __shfl_xor(a5, off);
        a6 += __shfl_xor(a6, off); a7 += __shfl_xor(a7, off);
    }
    float inv = 1.f / fmaxf((float)deg, 1.f);
    if (valid && lane < LP) {
        float4* Mp = (float4*)(M + (size_t)node * F + lane * 8);
        nts(Mp + 0, make_float4(a0 * inv, a1 * inv, a2 * inv, a3 * inv));
        nts(Mp + 1, make_float4(a4 * inv, a5 * inv, a6 * inv, a7 * inv));
    }
}

__device__ __forceinline__ float4 tanh4(float4 a) {
    return make_float4(tanhf(a.x), tanhf(a.y), tanhf(a.z), tanhf(a.w));
}

// ---------------- dense forward (output-tiled): out = tanh(M@wl + X@wr + b) ----------------
template <int FIN, int FOUT, int OTILE, int EMIT>
__global__ __launch_bounds__(256, 4)
void dense_fwd_kernel(const float* __restrict__ M,
                      const float* __restrict__ X,
                      const float* __restrict__ wl,
                      const float* __restrict__ bl,
                      const float* __restrict__ wr,
                      float* __restrict__ out,
                      void* __restrict__ emit, int n) {
    constexpr int OT4 = OTILE / 4;
    const int to = blockIdx.y * OTILE;
    __shared__ float4 s_wl[FIN * OT4];
    __shared__ float4 s_wr[FIN * OT4];
    __shared__ float4 s_b[OT4];
    for (int t = threadIdx.x; t < FIN * OT4; t += blockDim.x) {
        int f = t / OT4, j = t % OT4;
        s_wl[t] = ((const float4*)(wl + f * FOUT + to))[j];
        s_wr[t] = ((const float4*)(wr + f * FOUT + to))[j];
    }
    for (int t = threadIdx.x; t < OT4; t += blockDim.x)
        s_b[t] = ((const float4*)(bl + to))[t];
    __syncthreads();
    int i = blockIdx.x * blockDim.x + threadIdx.x;
    if (i >= n) return;

    float4 acc[OT4];
    #pragma unroll
    for (int oc = 0; oc < OT4; ++oc) acc[oc] = s_b[oc];
    const float4* M4 = (const float4*)M + (size_t)i * (FIN / 4);
    const float4* X4 = (const float4*)X + (size_t)i * (FIN / 4);
    #pragma unroll 2
    for (int fc = 0; fc < FIN / 4; ++fc) {
        float4 mv = M4[fc];
        float4 xv = X4[fc];
        #pragma unroll
        for (int c = 0; c < 4; ++c) {
            float mf = c == 0 ? mv.x : c == 1 ? mv.y : c == 2 ? mv.z : mv.w;
            float xf = c == 0 ? xv.x : c == 1 ? xv.y : c == 2 ? xv.z : xv.w;
            int f = fc * 4 + c;
            #pragma unroll
            for (int oc = 0; oc < OT4; ++oc) {
                float4 a = s_wl[f * OT4 + oc];
                float4 b = s_wr[f * OT4 + oc];
                acc[oc].x += mf * a.x + xf * b.x;
                acc[oc].y += mf * a.y + xf * b.y;
                acc[oc].z += mf * a.z + xf * b.z;
                acc[oc].w += mf * a.w + xf * b.w;
            }
        }
    }
    float4* o4 = (float4*)(out + (size_t)i * FOUT + to);
    #pragma unroll
    for (int oc = 0; oc < OT4; ++oc) {
        acc[oc] = tanh4(acc[oc]);
        nts(o4 + oc, acc[oc]);
    }
    if (EMIT == 1) {
        uint4* e4 = (uint4*)((u16*)emit + (size_t)i * FOUT + to);
        #pragma unroll
        for (int g = 0; g < OTILE / 8; ++g) {
            uint4 q;
            q.x = pack2(acc[2 * g].x, acc[2 * g].y);
            q.y = pack2(acc[2 * g].z, acc[2 * g].w);
            q.z = pack2(acc[2 * g + 1].x, acc[2 * g + 1].y);
            q.w = pack2(acc[2 * g + 1].z, acc[2 * g + 1].w);
            nts(e4 + g, q);
        }
    } else if (EMIT == 2) {
        u32 w[OT4];
        #pragma unroll
        for (int oc = 0; oc < OT4; ++oc)
            w[oc] = pack4fp8(acc[oc].x, acc[oc].y, acc[oc].z, acc[oc].w);
        uint4* e4 = (uint4*)((u32*)emit + (size_t)i * (FOUT / 4) + to / 4);
        #pragma unroll
        for (int g = 0; g < OTILE / 16; ++g) {
            uint4 q;
            q.x = w[4 * g + 0]; q.y = w[4 * g + 1];
            q.z = w[4 * g + 2]; q.w = w[4 * g + 3];
            nts(e4 + g, q);
        }
    }
}

// ---------------- dense reverse (output-tiled): out = tanh(M + X@wr + b) + res ----------------
template <int FIN, int FOUT, int OTILE>
__global__ __launch_bounds__(256, 4)
void dense_rev_kernel(const float* __restrict__ M,   // N x FOUT (premult mean)
                      const float* __restrict__ X,   // N x FIN (self)
                      const float* __restrict__ bl,
                      const float* __restrict__ wr,
                      const float* __restrict__ res,
                      float* __restrict__ out, int n) {
    constexpr int OT4 = OTILE / 4;
    const int to = blockIdx.y * OTILE;
    __shared__ float4 s_wr[FIN * OT4];
    __shared__ float4 s_b[OT4];
    for (int t = threadIdx.x; t < FIN * OT4; t += blockDim.x) {
        int f = t / OT4, j = t % OT4;
        s_wr[t] = ((const float4*)(wr + f * FOUT + to))[j];
    }
    for (int t = threadIdx.x; t < OT4; t += blockDim.x)
        s_b[t] = ((const float4*)(bl + to))[t];
    __syncthreads();
    int i = blockIdx.x * blockDim.x + threadIdx.x;
    if (i >= n) return;

    const float4* M4 = (const float4*)(M + (size_t)i * FOUT + to);
    float4 acc[OT4];
    #pragma unroll
    for (int oc = 0; oc < OT4; ++oc) {
        float4 m = M4[oc];
        float4 b = s_b[oc];
        acc[oc] = make_float4(m.x + b.x, m.y + b.y, m.z + b.z, m.w + b.w);
    }
    const float4* X4 = (const float4*)X + (size_t)i * (FIN / 4);
    #pragma unroll 2
    for (int fc = 0; fc < FIN / 4; ++fc) {
        float4 xv = X4[fc];
        #pragma unroll
        for (int c = 0; c < 4; ++c) {
            float xf = c == 0 ? xv.x : c == 1 ? xv.y : c == 2 ? xv.z : xv.w;
            int f = fc * 4 + c;
            #pragma unroll
            for (int oc = 0; oc < OT4; ++oc) {
                float4 w = s_wr[f * OT4 + oc];
                acc[oc].x += xf * w.x; acc[oc].y += xf * w.y;
                acc[oc].z += xf * w.z; acc[oc].w += xf * w.w;
            }
        }
    }
    const float4* R4 = (const float4*)(res + (size_t)i * FOUT + to);
    float4* o4 = (float4*)(out + (size_t)i * FOUT + to);
    #pragma unroll
    for (int oc = 0; oc < OT4; ++oc) {
        float4 t = tanh4(acc[oc]);
        float4 r = R4[oc];
        nts(o4 + oc, make_float4(t.x + r.x, t.y + r.y, t.z + r.z, t.w + r.w));
    }
}

// ---------------- first conv (FIN=3): scalar wave-per-node ----------------
template <int FIN, int FOUT, int FP, bool RES>
__global__ void conv_small_kernel(const float* __restrict__ xin,
                                  const float* __restrict__ wl,
                                  const float* __restrict__ bl,
                                  const float* __restrict__ wr,
                                  const float* __restrict__ res,
                                  float* __restrict__ out,
                                  const int* __restrict__ row_ptr,
                                  const int* __restrict__ csr_src, int n) {
    __shared__ float s_wl[FIN * FOUT];
    __shared__ float s_wr[FIN * FOUT];
    __shared__ float s_bl[FOUT];
    for (int t = threadIdx.x; t < FIN * FOUT; t += blockDim.x) {
        s_wl[t] = wl[t]; s_wr[t] = wr[t];
    }
    for (int t = threadIdx.x; t < FOUT; t += blockDim.x) s_bl[t] = bl[t];
    __syncthreads();

    int wid = threadIdx.x >> 6, lane = threadIdx.x & 63;
    int node = blockIdx.x * (blockDim.x >> 6) + wid;
    bool valid = node < n;
    int node_c = valid ? node : (n - 1);
    const int slot = lane / FP;
    const int feat = lane % FP;
    const int NPI = 64 / FP;

    int rs = row_ptr[node_c];
    int deg = row_ptr[node_c + 1] - rs;

    float sum = 0.f;
    for (int base = 0; base < deg; base += 4 * NPI) {
        #pragma unroll
        for (int k = 0; k < 4; ++k) {
            int nb = base + k * NPI + slot;
            bool v = nb < deg;
            int ia = v ? rs + nb : 0;
            int s = csr_src[ia];
            float val = (feat < FIN) ? xin[(size_t)s * FIN + feat] : 0.f;
            if (v) sum += val;
        }
    }
    #pragma unroll
    for (int off = FP; off < 64; off <<= 1) sum += __shfl_xor(sum, off);

    float mval = sum / fmaxf((float)deg, 1.0f);
    float xself = (lane < FIN) ? xin[(size_t)node_c * FIN + lane] : 0.f;

    int ol = (lane < FOUT) ? lane : 0;
    float acc = s_bl[ol];
    #pragma unroll
    for (int f = 0; f < FIN; ++f) {
        float mf = __shfl(mval, f);
        float xf = __shfl(xself, f);
        acc += mf * s_wl[f * FOUT + ol] + xf * s_wr[f * FOUT + ol];
    }
    if (valid && lane < FOUT) {
        float v = tanhf(acc);
        if (RES) v += res[(size_t)node * FOUT + lane];
        out[(size_t)node * FOUT + lane] = v;
    }
}

// ---------------- fused MLP + softmax ----------------
__global__ __launch_bounds__(256, 4)
void mlp_kernel(const float* __restrict__ h,
                const float* __restrict__ w1, const float* __restrict__ b1,
                const float* __restrict__ w2, const float* __restrict__ b2,
                const float* __restrict__ w3, const float* __restrict__ b3,
                float* __restrict__ out, int n) {
    __shared__ float sw1[8 * 32], sb1[32], sw2[32 * 16], sb2[16], sw3[16 * 2], sb3[2];
    for (int t = threadIdx.x; t < 8 * 32; t += blockDim.x) sw1[t] = w1[t];
    for (int t = threadIdx.x; t < 32 * 16; t += blockDim.x) sw2[t] = w2[t];
    for (int t = threadIdx.x; t < 32; t += blockDim.x) sb1[t] = b1[t];
    for (int t = threadIdx.x; t < 16; t += blockDim.x) sb2[t] = b2[t];
    for (int t = threadIdx.x; t < 32; t += blockDim.x) {
        if (t < 16 * 2) sw3[t] = w3[t];
        if (t < 2) sb3[t] = b3[t];
    }
    __syncthreads();
    int i = blockIdx.x * blockDim.x + threadIdx.x;
    if (i >= n) return;

    float hv[8];
    #pragma unroll
    for (int f = 0; f < 8; ++f) hv[f] = h[(size_t)i * 8 + f];

    float a1[32];
    #pragma unroll
    for (int o = 0; o < 32; ++o) {
        float acc = sb1[o];
        #pragma unroll
        for (int f = 0; f < 8; ++f) acc += hv[f] * sw1[f * 32 + o];
        a1[o] = tanhf(acc);
    }
    float a2[16];
    #pragma unroll
    for (int o = 0; o < 16; ++o) {
        float acc = sb2[o];
        #pragma unroll
        for (int f = 0; f < 32; ++f) acc += a1[f] * sw2[f * 16 + o];
        a2[o] = tanhf(acc);
    }
    float o0 = sb3[0], o1 = sb3[1];
    #pragma unroll
    for (int f = 0; f < 16; ++f) {
        o0 += a2[f] * sw3[f * 2 + 0];
        o1 += a2[f] * sw3[f * 2 + 1];
    }
    float m = fmaxf(o0, o1);
    float e0 = expf(o0 - m), e1 = expf(o1 - m);
    float inv = 1.f / (e0 + e1);
    out[(size_t)i * 2 + 0] = e0 * inv;
    out[(size_t)i * 2 + 1] = e1 * inv;
}

// ---------------- launch ----------------
extern "C" void kernel_launch(void* const* d_in, const int* in_sizes, int n_in,
                              void* d_out, int out_size, void* d_ws, size_t ws_size,
                              hipStream_t stream) {
    const int N = in_sizes[0] / 3;
    const int E = in_sizes[1] / 2;

    const float* x = (const float*)d_in[0];
    const int* edge = (const int*)d_in[1];
    const int* e_src = edge;
    const int* e_dst = edge + E;

    const float* c_wl[7]; const float* c_bl[7]; const float* c_wr[7];
    for (int k = 0; k < 7; ++k) {
        c_wl[k] = (const float*)d_in[2 + 3 * k + 0];
        c_bl[k] = (const float*)d_in[2 + 3 * k + 1];
        c_wr[k] = (const float*)d_in[2 + 3 * k + 2];
    }
    const float* l1w = (const float*)d_in[23];
    const float* l1b = (const float*)d_in[24];
    const float* l2w = (const float*)d_in[25];
    const float* l2b = (const float*)d_in[26];
    const float* l3w = (const float*)d_in[27];
    const float* l3b = (const float*)d_in[28];
    float* out = (float*)d_out;

    char* ws = (char*)d_ws;
    size_t off = 0;
    auto alloc = [&](size_t bytes) -> char* {
        char* p = ws + off;
        off = (off + bytes + 255) & ~(size_t)255;
        return p;
    };
    float* part = (float*)alloc(11 * STAT_BLOCKS * sizeof(float));
    float* stats = (float*)alloc(16 * sizeof(float));
    float* h0 = (float*)alloc((size_t)N * 3 * sizeof(float));
    float* x1 = (float*)alloc((size_t)N * 8 * sizeof(float));
    float* x2 = (float*)alloc((size_t)N * 16 * sizeof(float));
    float* x3 = (float*)alloc((size_t)N * 32 * sizeof(float));
    float* x4 = (float*)alloc((size_t)N * 64 * sizeof(float));
    float* t5 = (float*)alloc((size_t)N * 32 * sizeof(float));
    float* t6 = (float*)alloc((size_t)N * 16 * sizeof(float));
    float* t7 = (float*)alloc((size_t)N * 8 * sizeof(float));
    float* M = (float*)alloc((size_t)N * 32 * sizeof(float));   // mean buffer / CSR part_hist
    int* deg = (int*)alloc((size_t)N * sizeof(int));
    int* row_ptr = (int*)alloc(((size_t)N + 1) * sizeof(int));
    int* bsum = (int*)alloc(1024 * sizeof(int));
    int* bscan = (int*)alloc(1024 * sizeof(int));
    int* csrmeta = (int*)alloc((2 * NCH * NR + 16) * sizeof(int));
    int* csr_src = (int*)alloc((size_t)E * sizeof(int));
    (void)ws_size;

    // CSR scratch aliases (all dead before the conv pipeline writes them):
    int* bdst = (int*)x4;                  // bucketed dst: E ints
    int* bsrc = (int*)x4 + E;              // bucketed src: E ints
    int* part_hist = (int*)M;              // NR*NSC*rn ints <= N*32 + 224
    int* counts = csrmeta;
    int* gof = csrmeta + NCH * NR;
    int* bb = csrmeta + 2 * NCH * NR;      // NR+1 bases

    // gather tables aliased into dead f32 regions (lifetimes verified):
    u16* xb1 = (u16*)t7;                 // bf16, live: after c1 .. agg_c2   (t7 written at dense_c3r)
    u16* xb2 = (u16*)t6;                 // bf16, live: dense_c2 .. agg_c3   (t6 written at dense_c2r)
    u32* xq3 = (u32*)t5;                 // fp8,  live: dense_c3 .. agg_c4   (t5 written at dense_c1r)
    u32* yq5 = (u32*)t6;                 // fp8,  live: premult_c1r .. agg_c1r (xb2 dead; t6 written at dense_c2r)
    u16* y6  = (u16*)x4;                 // bf16, live: premult_c2r .. agg_c2r (x4 dead after dense_c1r)
    u16* y7  = (u16*)x4 + (size_t)N * 16;// bf16, live: premult_c3r .. agg_c3r (disjoint from y6)

    const int BT = 256;
    const int nB_N = (N + BT - 1) / BT;

    stats_partial_kernel<<<STAT_BLOCKS, BT, 0, stream>>>(x, part, N);
    stats_final_kernel<<<1, 64, 0, stream>>>(part, stats, N);
    normalize_kernel<<<nB_N, BT, 0, stream>>>(x, stats, h0, N);

    // CSR build (radix partition + LDS histograms; no global atomics)
    const int rn = (N + NR - 1) / NR;
    const int ech = (E + NCH - 1) / NCH;
    cnt_kernel<<<NCH, BT, 0, stream>>>(e_dst, counts, E, ech, rn);
    boff_kernel<<<1, 64, 0, stream>>>(counts, gof, bb);
    scatter_kernel<<<NCH, BT, 0, stream>>>(e_src, e_dst, gof, bdst, bsrc, E, ech, rn);
    hist2_kernel<<<NR * NSC, BT, 0, stream>>>(bdst, bb, part_hist, rn, N);
    prefix2_kernel<<<nB_N, BT, 0, stream>>>(part_hist, deg, rn, N);
    const int nbScan = (N + SCAN_BS - 1) / SCAN_BS;
    scanA_kernel<<<nbScan, 256, 0, stream>>>(deg, bsum, N);
    scanB_kernel<<<1, 1024, 0, stream>>>(bsum, bscan, row_ptr + N, nbScan);
    scanC_kernel<<<nbScan, 256, 0, stream>>>(deg, bscan, row_ptr, N);
    fill2_kernel<<<NR * NSC, BT, 0, stream>>>(bdst, bsrc, bb, row_ptr, part_hist, csr_src, rn, N);

    const int WPB = 4;
    const int nB_W = (N + WPB - 1) / WPB;
    const int nB_W2 = (N + 2 * WPB - 1) / (2 * WPB);

    // c1: 3 -> 8 (fused wave-per-node, tiny)
    conv_small_kernel<3, 8, 4, false><<<nB_W, BT, 0, stream>>>(h0, c_wl[0], c_bl[0], c_wr[0], nullptr, x1, row_ptr, csr_src, N);
    cast_bf16_kernel<<<(N + BT - 1) / BT, BT, 0, stream>>>(x1, xb1, N);
    // c2: 8 -> 16 (agg2 bf16 + dense, emit bf16 table for c3)
    agg2_bf16_kernel<1><<<nB_W2, BT, 0, stream>>>(xb1, M, row_ptr, csr_src, N);
    dense_fwd_kernel<8, 16, 16, 1><<<dim3(nB_N, 1), BT, 0, stream>>>(M, x1, c_wl[1], c_bl[1], c_wr[1], x2, xb2, N);
    // c3: 16 -> 32 (agg bf16 + dense single-tile, emit fp8 table for c4)
    agg_bf16_kernel<16, 2><<<nB_W, BT, 0, stream>>>(xb2, M, row_ptr, csr_src, N);
    dense_fwd_kernel<16, 32, 32, 2><<<dim3(nB_N, 1), BT, 0, stream>>>(M, x2, c_wl[2], c_bl[2], c_wr[2], x3, xq3, N);
    // c4: 32 -> 64 (agg fp8 + dense single 64-wide tile)
    agg_fp8_kernel<32, 4><<<nB_W, BT, 0, stream>>>(xq3, M, row_ptr, csr_src, N);
    dense_fwd_kernel<32, 64, 64, 0><<<dim3(nB_N, 1), BT, 0, stream>>>(M, x3, c_wl[3], c_bl[3], c_wr[3], x4, nullptr, N);
    // c1r: 64 -> 32 (premult fp8 single-tile, agg fp8, dense rev single-tile + res x3)
    premult_fp8_kernel<64, 32, 32><<<dim3(nB_N, 1), BT, 0, stream>>>(x4, c_wl[4], yq5, N);
    agg_fp8_kernel<32, 4><<<nB_W, BT, 0, stream>>>(yq5, M, row_ptr, csr_src, N);
    dense_rev_kernel<64, 32, 32><<<dim3(nB_N, 1), BT, 0, stream>>>(M, x4, c_bl[4], c_wr[4], x3, t5, N);
    // c2r: 32 -> 16 (premult bf16, agg bf16, dense rev + res x2)
    premult_kernel<32, 16><<<nB_N, BT, 0, stream>>>(t5, c_wl[5], y6, N);
    agg_bf16_kernel<16, 2><<<nB_W, BT, 0, stream>>>(y6, M, row_ptr, csr_src, N);
    dense_rev_kernel<32, 16, 16><<<dim3(nB_N, 1), BT, 0, stream>>>(M, t5, c_bl[5], c_wr[5], x2, t6, N);
    // c3r: 16 -> 8 (premult bf16, agg2 bf16, dense rev + res x1)
    premult_kernel<16, 8><<<nB_N, BT, 0, stream>>>(t6, c_wl[6], y7, N);
    agg2_bf16_kernel<1><<<nB_W2, BT, 0, stream>>>(y7, M, row_ptr, csr_src, N);
    dense_rev_kernel<16, 8, 8><<<dim3(nB_N, 1), BT, 0, stream>>>(M, t6, c_bl[6], c_wr[6], x1, t7, N);

    mlp_kernel<<<nB_N, BT, 0, stream>>>(t7, l1w, l1b, l2w, l2b, l3w, l3b, out, N);
}

// Round 16
// 775.082 us; speedup vs baseline: 1.0923x; 1.0923x over previous
//
#include <hip/hip_runtime.h>
#include <math.h>

#define RC (-4.3711388e-08f)   // cosf(float32(pi/2))
#define RS (1.0f)              // sinf(float32(pi/2))
#define STAT_BLOCKS 240
#define SCAN_BS 1024
#define NCH 256                // partition chunks
#define NR 8                   // dst regions
#define NSC 32                 // subchunks per region (hist/fill)
#define RN_MAX 12512           // max bins per region (N <= 100096)

typedef unsigned int u32;
typedef unsigned short u16;
typedef float v2f __attribute__((ext_vector_type(2)));

// NOTE (R13/R15 post-mortems): nt stores regressed 2x (producer->consumer L2
// reuse is load-bearing); nt loads in fill2/hist2 also regressed (50->80us).
// Plain loads/stores everywhere. (256,2) launch bounds: (256,4) broke dense c2.
__device__ __forceinline__ void nts(float4* p, float4 v) { *p = v; }
__device__ __forceinline__ void nts(uint4* p, uint4 v) { *p = v; }

__device__ __forceinline__ u16 f2bf(float f) {
    u32 u = __float_as_uint(f);
    u += 0x7FFFu + ((u >> 16) & 1u);
    return (u16)(u >> 16);
}
__device__ __forceinline__ u32 pack2(float lo, float hi) {
    return (u32)f2bf(lo) | ((u32)f2bf(hi) << 16);
}
__device__ __forceinline__ float bfl(u32 u) { return __uint_as_float(u << 16); }
__device__ __forceinline__ float bfh(u32 u) { return __uint_as_float(u & 0xFFFF0000u); }

__device__ __forceinline__ u32 pack4fp8(float a, float b, float c, float d) {
    int v = 0;
    v = __builtin_amdgcn_cvt_pk_fp8_f32(a, b, v, false);
    v = __builtin_amdgcn_cvt_pk_fp8_f32(c, d, v, true);
    return (u32)v;
}

// ---------------- normalize ----------------
__global__ void stats_partial_kernel(const float* __restrict__ x,
                                     float* __restrict__ part, int n) {
    float s0 = 0.f, s1 = 0.f, sr0 = 0.f, sr1 = 0.f;
    float mx0 = -1e30f, mn0 = 1e30f, mx1 = -1e30f, mn1 = 1e30f;
    float mxr0 = -1e30f, mxr1 = -1e30f, mxA = -1e30f;
    for (int i = blockIdx.x * blockDim.x + threadIdx.x; i < n;
         i += gridDim.x * blockDim.x) {
        float c0 = x[i * 3 + 0], c1 = x[i * 3 + 1], a = x[i * 3 + 2];
        float r0 = RC * c0 - RS * c1;
        float r1 = RS * c0 + RC * c1;
        s0 += c0; s1 += c1; sr0 += r0; sr1 += r1;
        mx0 = fmaxf(mx0, c0); mn0 = fminf(mn0, c0);
        mx1 = fmaxf(mx1, c1); mn1 = fminf(mn1, c1);
        mxr0 = fmaxf(mxr0, r0); mxr1 = fmaxf(mxr1, r1);
        mxA = fmaxf(mxA, a);
    }
    #pragma unroll
    for (int off = 32; off > 0; off >>= 1) {
        s0 += __shfl_down(s0, off);
        s1 += __shfl_down(s1, off);
        sr0 += __shfl_down(sr0, off);
        sr1 += __shfl_down(sr1, off);
        mx0 = fmaxf(mx0, __shfl_down(mx0, off));
        mn0 = fminf(mn0, __shfl_down(mn0, off));
        mx1 = fmaxf(mx1, __shfl_down(mx1, off));
        mn1 = fminf(mn1, __shfl_down(mn1, off));
        mxr0 = fmaxf(mxr0, __shfl_down(mxr0, off));
        mxr1 = fmaxf(mxr1, __shfl_down(mxr1, off));
        mxA = fmaxf(mxA, __shfl_down(mxA, off));
    }
    __shared__ float sh[11][4];
    int wid = threadIdx.x >> 6, lane = threadIdx.x & 63;
    if (lane == 0) {
        sh[0][wid] = s0; sh[1][wid] = s1; sh[2][wid] = sr0; sh[3][wid] = sr1;
        sh[4][wid] = mx0; sh[5][wid] = mn0; sh[6][wid] = mx1; sh[7][wid] = mn1;
        sh[8][wid] = mxr0; sh[9][wid] = mxr1; sh[10][wid] = mxA;
    }
    __syncthreads();
    if (threadIdx.x == 0) {
        float v[11];
        #pragma unroll
        for (int k = 0; k < 4; ++k) v[k] = sh[k][0] + sh[k][1] + sh[k][2] + sh[k][3];
        v[4] = fmaxf(fmaxf(sh[4][0], sh[4][1]), fmaxf(sh[4][2], sh[4][3]));
        v[5] = fminf(fminf(sh[5][0], sh[5][1]), fminf(sh[5][2], sh[5][3]));
        v[6] = fmaxf(fmaxf(sh[6][0], sh[6][1]), fmaxf(sh[6][2], sh[6][3]));
        v[7] = fminf(fminf(sh[7][0], sh[7][1]), fminf(sh[7][2], sh[7][3]));
        #pragma unroll
        for (int k = 8; k < 11; ++k)
            v[k] = fmaxf(fmaxf(sh[k][0], sh[k][1]), fmaxf(sh[k][2], sh[k][3]));
        #pragma unroll
        for (int k = 0; k < 11; ++k) part[k * STAT_BLOCKS + blockIdx.x] = v[k];
    }
}

__global__ void stats_final_kernel(const float* __restrict__ part,
                                   float* __restrict__ stats, int n) {
    __shared__ float red[11];
    int t = threadIdx.x;
    if (t < 11) {
        float v;
        if (t < 4) {
            v = 0.f;
            for (int b = 0; b < STAT_BLOCKS; ++b) v += part[t * STAT_BLOCKS + b];
        } else if (t == 5 || t == 7) {
            v = 1e30f;
            for (int b = 0; b < STAT_BLOCKS; ++b) v = fminf(v, part[t * STAT_BLOCKS + b]);
        } else {
            v = -1e30f;
            for (int b = 0; b < STAT_BLOCKS; ++b) v = fmaxf(v, part[t * STAT_BLOCKS + b]);
        }
        red[t] = v;
    }
    __syncthreads();
    if (t == 0) {
        float range0 = red[4] - red[5];
        float range1 = red[6] - red[7];
        bool rot = range1 > range0;
        stats[0] = rot ? 1.f : 0.f;
        stats[1] = (rot ? red[2] : red[0]) / (float)n;
        stats[2] = (rot ? red[3] : red[1]) / (float)n;
        stats[3] = rot ? red[8] : red[4];
        stats[4] = rot ? red[9] : red[6];
        stats[5] = red[10];
    }
}

__global__ void normalize_kernel(const float* __restrict__ x,
                                 const float* __restrict__ stats,
                                 float* __restrict__ h0, int n) {
    int i = blockIdx.x * blockDim.x + threadIdx.x;
    if (i >= n) return;
    float c0 = x[i * 3 + 0], c1 = x[i * 3 + 1], a = x[i * 3 + 2];
    if (stats[0] != 0.f) {
        float r0 = RC * c0 - RS * c1;
        float r1 = RS * c0 + RC * c1;
        c0 = r0; c1 = r1;
    }
    h0[i * 3 + 0] = (c0 - stats[1]) / stats[3];
    h0[i * 3 + 1] = (c1 - stats[2]) / stats[4];
    h0[i * 3 + 2] = a / stats[5];
}

// ---------------- CSR build: radix-partition + LDS histogram ----------------
__global__ void cnt_kernel(const int* __restrict__ dst, int* __restrict__ counts,
                           int e, int ech, int rn) {
    int c = blockIdx.x;
    int cnt[NR];
    #pragma unroll
    for (int k = 0; k < NR; ++k) cnt[k] = 0;
    int start = c * ech, end = min(start + ech, e);
    for (int i = start + threadIdx.x; i < end; i += blockDim.x) {
        int r = dst[i] / rn;
        #pragma unroll
        for (int k = 0; k < NR; ++k) cnt[k] += (r == k) ? 1 : 0;
    }
    __shared__ int sh[NR];
    if (threadIdx.x < NR) sh[threadIdx.x] = 0;
    __syncthreads();
    #pragma unroll
    for (int k = 0; k < NR; ++k)
        if (cnt[k]) atomicAdd(&sh[k], cnt[k]);
    __syncthreads();
    if (threadIdx.x < NR) counts[c * NR + threadIdx.x] = sh[threadIdx.x];
}

__global__ void boff_kernel(const int* __restrict__ counts, int* __restrict__ gof,
                            int* __restrict__ bb) {
    __shared__ int sbb[NR + 1];
    __shared__ int rt[NR];
    int t = threadIdx.x;
    if (t < NR) {
        int run = 0;
        for (int c = 0; c < NCH; ++c) {
            gof[c * NR + t] = run;
            run += counts[c * NR + t];
        }
        rt[t] = run;
    }
    __syncthreads();
    if (t == 0) {
        int b = 0;
        for (int r = 0; r < NR; ++r) { sbb[r] = b; b += rt[r]; }
        sbb[NR] = b;
        for (int r = 0; r <= NR; ++r) bb[r] = sbb[r];
    }
    __syncthreads();
    if (t < NR) {
        int b = sbb[t];
        for (int c = 0; c < NCH; ++c) gof[c * NR + t] += b;
    }
}

__global__ void scatter_kernel(const int* __restrict__ src, const int* __restrict__ dst,
                               const int* __restrict__ gof,
                               int* __restrict__ bdst, int* __restrict__ bsrc,
                               int e, int ech, int rn) {
    __shared__ int cur[NR];
    int c = blockIdx.x;
    if (threadIdx.x < NR) cur[threadIdx.x] = gof[c * NR + threadIdx.x];
    __syncthreads();
    int start = c * ech, end = min(start + ech, e);
    for (int i = start + threadIdx.x; i < end; i += blockDim.x) {
        int d = dst[i];
        int s = src[i];
        int r = d / rn;
        int p = atomicAdd(&cur[r], 1);
        bdst[p] = d;
        bsrc[p] = s;
    }
}

__global__ void hist2_kernel(const int* __restrict__ bdst, const int* __restrict__ bb,
                             int* __restrict__ part_hist, int rn, int n) {
    __shared__ int hist[RN_MAX];
    int r = blockIdx.x & (NR - 1);
    int sc = blockIdx.x >> 3;
    int lo = bb[r], hi = bb[r + 1];
    int clen = (hi - lo + NSC - 1) / NSC;
    int start = lo + sc * clen, end = min(start + clen, hi);
    int base = r * rn;
    int cnt = min(rn, n - base);
    if (cnt <= 0) return;
    for (int t = threadIdx.x; t < cnt; t += blockDim.x) hist[t] = 0;
    __syncthreads();
    for (int i = start + threadIdx.x; i < end; i += blockDim.x)
        atomicAdd(&hist[bdst[i] - base], 1);
    __syncthreads();
    int* outp = part_hist + ((size_t)(r * NSC + sc)) * rn;
    for (int t = threadIdx.x; t < cnt; t += blockDim.x) outp[t] = hist[t];
}

__global__ void prefix2_kernel(int* __restrict__ part_hist, int* __restrict__ deg,
                               int rn, int n) {
    int node = blockIdx.x * blockDim.x + threadIdx.x;
    if (node >= n) return;
    int r = node / rn, lb = node - r * rn;
    int* p = part_hist + ((size_t)(r * NSC)) * rn + lb;
    int run = 0;
    #pragma unroll 4
    for (int sc = 0; sc < NSC; ++sc) {
        int v = p[(size_t)sc * rn];
        p[(size_t)sc * rn] = run;
        run += v;
    }
    deg[node] = run;
}

__global__ void fill2_kernel(const int* __restrict__ bdst, const int* __restrict__ bsrc,
                             const int* __restrict__ bb, const int* __restrict__ row_ptr,
                             const int* __restrict__ part_hist, int* __restrict__ csr_src,
                             int rn, int n) {
    __shared__ int hist[RN_MAX];
    int r = blockIdx.x & (NR - 1);
    int sc = blockIdx.x >> 3;
    int lo = bb[r], hi = bb[r + 1];
    int clen = (hi - lo + NSC - 1) / NSC;
    int start = lo + sc * clen, end = min(start + clen, hi);
    int base = r * rn;
    int cnt = min(rn, n - base);
    if (cnt <= 0) return;
    for (int t = threadIdx.x; t < cnt; t += blockDim.x) hist[t] = 0;
    __syncthreads();
    const int* pref = part_hist + ((size_t)(r * NSC + sc)) * rn;
    for (int i = start + threadIdx.x; i < end; i += blockDim.x) {
        int d = bdst[i];
        int lb = d - base;
        int lr = atomicAdd(&hist[lb], 1);
        csr_src[row_ptr[d] + pref[lb] + lr] = bsrc[i];
    }
}

__global__ void scanA_kernel(const int* __restrict__ deg, int* __restrict__ bsum, int n) {
    __shared__ int sh[256];
    int b = blockIdx.x, t = threadIdx.x;
    int base = b * SCAN_BS + t * 4;
    int s = 0;
    if (base + 3 < n) {
        int4 v = *(const int4*)(deg + base);
        s = v.x + v.y + v.z + v.w;
    } else {
        for (int k = 0; k < 4; ++k) if (base + k < n) s += deg[base + k];
    }
    sh[t] = s; __syncthreads();
    for (int o = 128; o > 0; o >>= 1) {
        if (t < o) sh[t] += sh[t + o];
        __syncthreads();
    }
    if (t == 0) bsum[b] = sh[0];
}

__global__ void scanB_kernel(const int* __restrict__ bsum, int* __restrict__ bscan,
                             int* __restrict__ row_ptr_n, int nb) {
    __shared__ int sh[1024];
    int t = threadIdx.x;
    int v = (t < nb) ? bsum[t] : 0;
    sh[t] = v; __syncthreads();
    for (int o = 1; o < 1024; o <<= 1) {
        int u = (t >= o) ? sh[t - o] : 0;
        __syncthreads();
        sh[t] += u;
        __syncthreads();
    }
    if (t < nb) bscan[t] = sh[t] - v;
    if (t == nb - 1) row_ptr_n[0] = sh[t];
}

__global__ void scanC_kernel(const int* __restrict__ deg, const int* __restrict__ bscan,
                             int* __restrict__ row_ptr, int n) {
    __shared__ int sh[256];
    int b = blockIdx.x, t = threadIdx.x;
    int base = b * SCAN_BS + t * 4;
    int v0 = 0, v1 = 0, v2 = 0, v3 = 0;
    if (base + 3 < n) {
        int4 v = *(const int4*)(deg + base);
        v0 = v.x; v1 = v.y; v2 = v.z; v3 = v.w;
    } else {
        if (base < n) v0 = deg[base];
        if (base + 1 < n) v1 = deg[base + 1];
        if (base + 2 < n) v2 = deg[base + 2];
        if (base + 3 < n) v3 = deg[base + 3];
    }
    int s = v0 + v1 + v2 + v3;
    sh[t] = s; __syncthreads();
    for (int o = 1; o < 256; o <<= 1) {
        int u = (t >= o) ? sh[t - o] : 0;
        __syncthreads();
        sh[t] += u;
        __syncthreads();
    }
    int ex = sh[t] - s + bscan[b];
    if (base < n)     row_ptr[base] = ex;
    if (base + 1 < n) row_ptr[base + 1] = ex + v0;
    if (base + 2 < n) row_ptr[base + 2] = ex + v0 + v1;
    if (base + 3 < n) row_ptr[base + 3] = ex + v0 + v1 + v2;
}

// ---------------- cast f32 -> bf16 (8 elems/thread) ----------------
__global__ void cast_bf16_kernel(const float* __restrict__ xin,
                                 u16* __restrict__ xb, int n8) {
    int i = blockIdx.x * blockDim.x + threadIdx.x;
    if (i >= n8) return;
    const float4* a = (const float4*)xin + (size_t)i * 2;
    float4 v0 = a[0], v1 = a[1];
    uint4 q;
    q.x = pack2(v0.x, v0.y); q.y = pack2(v0.z, v0.w);
    q.z = pack2(v1.x, v1.y); q.w = pack2(v1.z, v1.w);
    nts((uint4*)xb + i, q);
}

// ---------------- premultiply: y = x @ wl, output bf16 ----------------
template <int FIN, int FOUT>
__global__ __launch_bounds__(256, 2)
void premult_kernel(const float* __restrict__ xin,
                    const float* __restrict__ wl,
                    u16* __restrict__ y, int n) {
    __shared__ float4 s_w[FIN * FOUT / 4];
    for (int t = threadIdx.x; t < FIN * FOUT / 4; t += blockDim.x)
        s_w[t] = ((const float4*)wl)[t];
    __syncthreads();
    int i = blockIdx.x * blockDim.x + threadIdx.x;
    if (i >= n) return;
    float4 acc[FOUT / 4];
    #pragma unroll
    for (int oc = 0; oc < FOUT / 4; ++oc) acc[oc] = make_float4(0.f, 0.f, 0.f, 0.f);
    const float4* x4 = (const float4*)xin + (size_t)i * (FIN / 4);
    #pragma unroll 2
    for (int fc = 0; fc < FIN / 4; ++fc) {
        float4 xv = x4[fc];
        #pragma unroll
        for (int c = 0; c < 4; ++c) {
            float xf = c == 0 ? xv.x : c == 1 ? xv.y : c == 2 ? xv.z : xv.w;
            int f = fc * 4 + c;
            #pragma unroll
            for (int oc = 0; oc < FOUT / 4; ++oc) {
                float4 w = s_w[f * (FOUT / 4) + oc];
                acc[oc].x += xf * w.x; acc[oc].y += xf * w.y;
                acc[oc].z += xf * w.z; acc[oc].w += xf * w.w;
            }
        }
    }
    uint4* y4 = (uint4*)(y + (size_t)i * FOUT);
    #pragma unroll
    for (int g = 0; g < FOUT / 8; ++g) {
        uint4 q;
        q.x = pack2(acc[2 * g].x, acc[2 * g].y);
        q.y = pack2(acc[2 * g].z, acc[2 * g].w);
        q.z = pack2(acc[2 * g + 1].x, acc[2 * g + 1].y);
        q.w = pack2(acc[2 * g + 1].z, acc[2 * g + 1].w);
        nts(y4 + g, q);
    }
}

// ---------------- premultiply: y = x @ wl, output fp8 (output-tiled) ----------------
template <int FIN, int FOUT, int OTILE>
__global__ __launch_bounds__(256, 2)
void premult_fp8_kernel(const float* __restrict__ xin,
                        const float* __restrict__ wl,
                        u32* __restrict__ y, int n) {
    constexpr int OT4 = OTILE / 4;
    const int to = blockIdx.y * OTILE;
    __shared__ float4 s_w[FIN * OT4];
    for (int t = threadIdx.x; t < FIN * OT4; t += blockDim.x) {
        int f = t / OT4, j = t % OT4;
        s_w[t] = ((const float4*)(wl + f * FOUT + to))[j];
    }
    __syncthreads();
    int i = blockIdx.x * blockDim.x + threadIdx.x;
    if (i >= n) return;
    float4 acc[OT4];
    #pragma unroll
    for (int oc = 0; oc < OT4; ++oc) acc[oc] = make_float4(0.f, 0.f, 0.f, 0.f);
    const float4* x4 = (const float4*)xin + (size_t)i * (FIN / 4);
    #pragma unroll 2
    for (int fc = 0; fc < FIN / 4; ++fc) {
        float4 xv = x4[fc];
        #pragma unroll
        for (int c = 0; c < 4; ++c) {
            float xf = c == 0 ? xv.x : c == 1 ? xv.y : c == 2 ? xv.z : xv.w;
            int f = fc * 4 + c;
            #pragma unroll
            for (int oc = 0; oc < OT4; ++oc) {
                float4 w = s_w[f * OT4 + oc];
                acc[oc].x += xf * w.x; acc[oc].y += xf * w.y;
                acc[oc].z += xf * w.z; acc[oc].w += xf * w.w;
            }
        }
    }
    u32 w[OT4];
    #pragma unroll
    for (int oc = 0; oc < OT4; ++oc)
        w[oc] = pack4fp8(acc[oc].x, acc[oc].y, acc[oc].z, acc[oc].w);
    uint4* y4 = (uint4*)(y + (size_t)i * (FOUT / 4) + to / 4);
    #pragma unroll
    for (int g = 0; g < OT4 / 4; ++g) {
        uint4 q;
        q.x = w[4 * g + 0]; q.y = w[4 * g + 1];
        q.z = w[4 * g + 2]; q.w = w[4 * g + 3];
        nts(y4 + g, q);
    }
}

// ---------------- agg: mean of gathered bf16 rows -> f32 M (1 node/wave) ----------------
template <int F, int U>
__global__ void agg_bf16_kernel(const u16* __restrict__ xb,
                                float* __restrict__ M,
                                const int* __restrict__ row_ptr,
                                const int* __restrict__ csr_src, int n) {
    constexpr int LP = F / 8;
    constexpr int NPI = 64 / LP;
    int wid = threadIdx.x >> 6, lane = threadIdx.x & 63;
    int node = blockIdx.x * (blockDim.x >> 6) + wid;
    bool valid = node < n;
    int node_c = valid ? node : (n - 1);
    int rs = row_ptr[node_c];
    int deg = row_ptr[node_c + 1] - rs;
    int slot = lane / LP, chunk = lane % LP;
    const uint4* xb4 = (const uint4*)xb;

    float a0 = 0.f, a1 = 0.f, a2 = 0.f, a3 = 0.f, a4 = 0.f, a5 = 0.f, a6 = 0.f, a7 = 0.f;
    for (int base = 0; base < deg; base += U * NPI) {
        #pragma unroll
        for (int k = 0; k < U; ++k) {
            int nb = base + k * NPI + slot;
            bool v = nb < deg;
            int ia = v ? rs + nb : 0;
            int s = csr_src[ia];
            uint4 q = xb4[(size_t)s * LP + chunk];
            if (v) {
                a0 += bfl(q.x); a1 += bfh(q.x); a2 += bfl(q.y); a3 += bfh(q.y);
                a4 += bfl(q.z); a5 += bfh(q.z); a6 += bfl(q.w); a7 += bfh(q.w);
            }
        }
    }
    #pragma unroll
    for (int off = LP; off < 64; off <<= 1) {
        a0 += __shfl_xor(a0, off); a1 += __shfl_xor(a1, off);
        a2 += __shfl_xor(a2, off); a3 += __shfl_xor(a3, off);
        a4 += __shfl_xor(a4, off); a5 += __shfl_xor(a5, off);
        a6 += __shfl_xor(a6, off); a7 += __shfl_xor(a7, off);
    }
    float inv = 1.f / fmaxf((float)deg, 1.f);
    if (valid && lane < LP) {
        float4* Mp = (float4*)(M + (size_t)node * F + lane * 8);
        nts(Mp + 0, make_float4(a0 * inv, a1 * inv, a2 * inv, a3 * inv));
        nts(Mp + 1, make_float4(a4 * inv, a5 * inv, a6 * inv, a7 * inv));
    }
}

// ---------------- agg2: F=8 bf16, 2 nodes per wave (32-lane halves) ----------------
template <int U>
__global__ void agg2_bf16_kernel(const u16* __restrict__ xb,
                                 float* __restrict__ M,
                                 const int* __restrict__ row_ptr,
                                 const int* __restrict__ csr_src, int n) {
    int wid = threadIdx.x >> 6, lane = threadIdx.x & 63;
    int half = lane >> 5;
    int sl = lane & 31;
    int node = (blockIdx.x * (blockDim.x >> 6) + wid) * 2 + half;
    bool valid = node < n;
    int node_c = valid ? node : (n - 1);
    int rs = row_ptr[node_c];
    int deg = row_ptr[node_c + 1] - rs;
    const uint4* xb4 = (const uint4*)xb;

    float a0 = 0.f, a1 = 0.f, a2 = 0.f, a3 = 0.f, a4 = 0.f, a5 = 0.f, a6 = 0.f, a7 = 0.f;
    for (int base = 0; base < deg; base += U * 32) {
        #pragma unroll
        for (int k = 0; k < U; ++k) {
            int nb = base + k * 32 + sl;
            bool v = nb < deg;
            int ia = v ? rs + nb : 0;
            int s = csr_src[ia];
            uint4 q = xb4[s];
            if (v) {
                a0 += bfl(q.x); a1 += bfh(q.x); a2 += bfl(q.y); a3 += bfh(q.y);
                a4 += bfl(q.z); a5 += bfh(q.z); a6 += bfl(q.w); a7 += bfh(q.w);
            }
        }
    }
    #pragma unroll
    for (int off = 1; off < 32; off <<= 1) {
        a0 += __shfl_xor(a0, off); a1 += __shfl_xor(a1, off);
        a2 += __shfl_xor(a2, off); a3 += __shfl_xor(a3, off);
        a4 += __shfl_xor(a4, off); a5 += __shfl_xor(a5, off);
        a6 += __shfl_xor(a6, off); a7 += __shfl_xor(a7, off);
    }
    float inv = 1.f / fmaxf((float)deg, 1.f);
    if (valid && sl == 0) {
        float4* Mp = (float4*)(M + (size_t)node * 8);
        nts(Mp + 0, make_float4(a0 * inv, a1 * inv, a2 * inv, a3 * inv));
        nts(Mp + 1, make_float4(a4 * inv, a5 * inv, a6 * inv, a7 * inv));
    }
}

// ---------------- agg: mean of gathered fp8 rows -> f32 M ----------------
template <int F, int U>
__global__ void agg_fp8_kernel(const u32* __restrict__ xq,
                               float* __restrict__ M,
                               const int* __restrict__ row_ptr,
                               const int* __restrict__ csr_src, int n) {
    constexpr int LP = F / 8;
    constexpr int NPI = 64 / LP;
    int wid = threadIdx.x >> 6, lane = threadIdx.x & 63;
    int node = blockIdx.x * (blockDim.x >> 6) + wid;
    bool valid = node < n;
    int node_c = valid ? node : (n - 1);
    int rs = row_ptr[node_c];
    int deg = row_ptr[node_c + 1] - rs;
    int slot = lane / LP, chunk = lane % LP;
    const uint2* xq2 = (const uint2*)xq;

    float a0 = 0.f, a1 = 0.f, a2 = 0.f, a3 = 0.f, a4 = 0.f, a5 = 0.f, a6 = 0.f, a7 = 0.f;
    for (int base = 0; base < deg; base += U * NPI) {
        #pragma unroll
        for (int k = 0; k < U; ++k) {
            int nb = base + k * NPI + slot;
            bool v = nb < deg;
            int ia = v ? rs + nb : 0;
            int s = csr_src[ia];
            uint2 q = xq2[(size_t)s * LP + chunk];
            if (v) {
                v2f p0 = __builtin_amdgcn_cvt_pk_f32_fp8(q.x, false);
                v2f p1 = __builtin_amdgcn_cvt_pk_f32_fp8(q.x, true);
                v2f p2 = __builtin_amdgcn_cvt_pk_f32_fp8(q.y, false);
                v2f p3 = __builtin_amdgcn_cvt_pk_f32_fp8(q.y, true);
                a0 += p0.x; a1 += p0.y; a2 += p1.x; a3 += p1.y;
                a4 += p2.x; a5 += p2.y; a6 += p3.x; a7 += p3.y;
            }
        }
    }
    #pragma unroll
    for (int off = LP; off < 64; off <<= 1) {
        a0 += __shfl_xor(a0, off); a1 += __shfl_xor(a1, off);
        a2 += __shfl_xor(a2, off); a3 += __shfl_xor(a3, off);
        a4 += __shfl_xor(a4, off); a5 += __shfl_xor(a5, off);
        a6 += __shfl_xor(a6, off); a7 += __shfl_xor(a7, off);
    }
    float inv = 1.f / fmaxf((float)deg, 1.f);
    if (valid && lane < LP) {
        float4* Mp = (float4*)(M + (size_t)node * F + lane * 8);
        nts(Mp + 0, make_float4(a0 * inv, a1 * inv, a2 * inv, a3 * inv));
        nts(Mp + 1, make_float4(a4 * inv, a5 * inv, a6 * inv, a7 * inv));
    }
}

__device__ __forceinline__ float4 tanh4(float4 a) {
    return make_float4(tanhf(a.x), tanhf(a.y), tanhf(a.z), tanhf(a.w));
}

// ---------------- dense forward (output-tiled): out = tanh(M@wl + X@wr + b) ----------------
template <int FIN, int FOUT, int OTILE, int EMIT>
__global__ __launch_bounds__(256, 2)
void dense_fwd_kernel(const float* __restrict__ M,
                      const float* __restrict__ X,
                      const float* __restrict__ wl,
                      const float* __restrict__ bl,
                      const float* __restrict__ wr,
                      float* __restrict__ out,
                      void* __restrict__ emit, int n) {
    constexpr int OT4 = OTILE / 4;
    const int to = blockIdx.y * OTILE;
    __shared__ float4 s_wl[FIN * OT4];
    __shared__ float4 s_wr[FIN * OT4];
    __shared__ float4 s_b[OT4];
    for (int t = threadIdx.x; t < FIN * OT4; t += blockDim.x) {
        int f = t / OT4, j = t % OT4;
        s_wl[t] = ((const float4*)(wl + f * FOUT + to))[j];
        s_wr[t] = ((const float4*)(wr + f * FOUT + to))[j];
    }
    for (int t = threadIdx.x; t < OT4; t += blockDim.x)
        s_b[t] = ((const float4*)(bl + to))[t];
    __syncthreads();
    int i = blockIdx.x * blockDim.x + threadIdx.x;
    if (i >= n) return;

    float4 acc[OT4];
    #pragma unroll
    for (int oc = 0; oc < OT4; ++oc) acc[oc] = s_b[oc];
    const float4* M4 = (const float4*)M + (size_t)i * (FIN / 4);
    const float4* X4 = (const float4*)X + (size_t)i * (FIN / 4);
    #pragma unroll 2
    for (int fc = 0; fc < FIN / 4; ++fc) {
        float4 mv = M4[fc];
        float4 xv = X4[fc];
        #pragma unroll
        for (int c = 0; c < 4; ++c) {
            float mf = c == 0 ? mv.x : c == 1 ? mv.y : c == 2 ? mv.z : mv.w;
            float xf = c == 0 ? xv.x : c == 1 ? xv.y : c == 2 ? xv.z : xv.w;
            int f = fc * 4 + c;
            #pragma unroll
            for (int oc = 0; oc < OT4; ++oc) {
                float4 a = s_wl[f * OT4 + oc];
                float4 b = s_wr[f * OT4 + oc];
                acc[oc].x += mf * a.x + xf * b.x;
                acc[oc].y += mf * a.y + xf * b.y;
                acc[oc].z += mf * a.z + xf * b.z;
                acc[oc].w += mf * a.w + xf * b.w;
            }
        }
    }
    float4* o4 = (float4*)(out + (size_t)i * FOUT + to);
    #pragma unroll
    for (int oc = 0; oc < OT4; ++oc) {
        acc[oc] = tanh4(acc[oc]);
        nts(o4 + oc, acc[oc]);
    }
    if (EMIT == 1) {
        uint4* e4 = (uint4*)((u16*)emit + (size_t)i * FOUT + to);
        #pragma unroll
        for (int g = 0; g < OTILE / 8; ++g) {
            uint4 q;
            q.x = pack2(acc[2 * g].x, acc[2 * g].y);
            q.y = pack2(acc[2 * g].z, acc[2 * g].w);
            q.z = pack2(acc[2 * g + 1].x, acc[2 * g + 1].y);
            q.w = pack2(acc[2 * g + 1].z, acc[2 * g + 1].w);
            nts(e4 + g, q);
        }
    } else if (EMIT == 2) {
        u32 w[OT4];
        #pragma unroll
        for (int oc = 0; oc < OT4; ++oc)
            w[oc] = pack4fp8(acc[oc].x, acc[oc].y, acc[oc].z, acc[oc].w);
        uint4* e4 = (uint4*)((u32*)emit + (size_t)i * (FOUT / 4) + to / 4);
        #pragma unroll
        for (int g = 0; g < OTILE / 16; ++g) {
            uint4 q;
            q.x = w[4 * g + 0]; q.y = w[4 * g + 1];
            q.z = w[4 * g + 2]; q.w = w[4 * g + 3];
            nts(e4 + g, q);
        }
    }
}

// ---------------- dense reverse (output-tiled): out = tanh(M + X@wr + b) + res ----------------
template <int FIN, int FOUT, int OTILE>
__global__ __launch_bounds__(256, 2)
void dense_rev_kernel(const float* __restrict__ M,   // N x FOUT (premult mean)
                      const float* __restrict__ X,   // N x FIN (self)
                      const float* __restrict__ bl,
                      const float* __restrict__ wr,
                      const float* __restrict__ res,
                      float* __restrict__ out, int n) {
    constexpr int OT4 = OTILE / 4;
    const int to = blockIdx.y * OTILE;
    __shared__ float4 s_wr[FIN * OT4];
    __shared__ float4 s_b[OT4];
    for (int t = threadIdx.x; t < FIN * OT4; t += blockDim.x) {
        int f = t / OT4, j = t % OT4;
        s_wr[t] = ((const float4*)(wr + f * FOUT + to))[j];
    }
    for (int t = threadIdx.x; t < OT4; t += blockDim.x)
        s_b[t] = ((const float4*)(bl + to))[t];
    __syncthreads();
    int i = blockIdx.x * blockDim.x + threadIdx.x;
    if (i >= n) return;

    const float4* M4 = (const float4*)(M + (size_t)i * FOUT + to);
    float4 acc[OT4];
    #pragma unroll
    for (int oc = 0; oc < OT4; ++oc) {
        float4 m = M4[oc];
        float4 b = s_b[oc];
        acc[oc] = make_float4(m.x + b.x, m.y + b.y, m.z + b.z, m.w + b.w);
    }
    const float4* X4 = (const float4*)X + (size_t)i * (FIN / 4);
    #pragma unroll 2
    for (int fc = 0; fc < FIN / 4; ++fc) {
        float4 xv = X4[fc];
        #pragma unroll
        for (int c = 0; c < 4; ++c) {
            float xf = c == 0 ? xv.x : c == 1 ? xv.y : c == 2 ? xv.z : xv.w;
            int f = fc * 4 + c;
            #pragma unroll
            for (int oc = 0; oc < OT4; ++oc) {
                float4 w = s_wr[f * OT4 + oc];
                acc[oc].x += xf * w.x; acc[oc].y += xf * w.y;
                acc[oc].z += xf * w.z; acc[oc].w += xf * w.w;
            }
        }
    }
    const float4* R4 = (const float4*)(res + (size_t)i * FOUT + to);
    float4* o4 = (float4*)(out + (size_t)i * FOUT + to);
    #pragma unroll
    for (int oc = 0; oc < OT4; ++oc) {
        float4 t = tanh4(acc[oc]);
        float4 r = R4[oc];
        nts(o4 + oc, make_float4(t.x + r.x, t.y + r.y, t.z + r.z, t.w + r.w));
    }
}

// ---------------- first conv (FIN=3): scalar wave-per-node ----------------
template <int FIN, int FOUT, int FP, bool RES>
__global__ void conv_small_kernel(const float* __restrict__ xin,
                                  const float* __restrict__ wl,
                                  const float* __restrict__ bl,
                                  const float* __restrict__ wr,
                                  const float* __restrict__ res,
                                  float* __restrict__ out,
                                  const int* __restrict__ row_ptr,
                                  const int* __restrict__ csr_src, int n) {
    __shared__ float s_wl[FIN * FOUT];
    __shared__ float s_wr[FIN * FOUT];
    __shared__ float s_bl[FOUT];
    for (int t = threadIdx.x; t < FIN * FOUT; t += blockDim.x) {
        s_wl[t] = wl[t]; s_wr[t] = wr[t];
    }
    for (int t = threadIdx.x; t < FOUT; t += blockDim.x) s_bl[t] = bl[t];
    __syncthreads();

    int wid = threadIdx.x >> 6, lane = threadIdx.x & 63;
    int node = blockIdx.x * (blockDim.x >> 6) + wid;
    bool valid = node < n;
    int node_c = valid ? node : (n - 1);
    const int slot = lane / FP;
    const int feat = lane % FP;
    const int NPI = 64 / FP;

    int rs = row_ptr[node_c];
    int deg = row_ptr[node_c + 1] - rs;

    float sum = 0.f;
    for (int base = 0; base < deg; base += 4 * NPI) {
        #pragma unroll
        for (int k = 0; k < 4; ++k) {
            int nb = base + k * NPI + slot;
            bool v = nb < deg;
            int ia = v ? rs + nb : 0;
            int s = csr_src[ia];
            float val = (feat < FIN) ? xin[(size_t)s * FIN + feat] : 0.f;
            if (v) sum += val;
        }
    }
    #pragma unroll
    for (int off = FP; off < 64; off <<= 1) sum += __shfl_xor(sum, off);

    float mval = sum / fmaxf((float)deg, 1.0f);
    float xself = (lane < FIN) ? xin[(size_t)node_c * FIN + lane] : 0.f;

    int ol = (lane < FOUT) ? lane : 0;
    float acc = s_bl[ol];
    #pragma unroll
    for (int f = 0; f < FIN; ++f) {
        float mf = __shfl(mval, f);
        float xf = __shfl(xself, f);
        acc += mf * s_wl[f * FOUT + ol] + xf * s_wr[f * FOUT + ol];
    }
    if (valid && lane < FOUT) {
        float v = tanhf(acc);
        if (RES) v += res[(size_t)node * FOUT + lane];
        out[(size_t)node * FOUT + lane] = v;
    }
}

// ---------------- fused MLP + softmax ----------------
__global__ __launch_bounds__(256, 2)
void mlp_kernel(const float* __restrict__ h,
                const float* __restrict__ w1, const float* __restrict__ b1,
                const float* __restrict__ w2, const float* __restrict__ b2,
                const float* __restrict__ w3, const float* __restrict__ b3,
                float* __restrict__ out, int n) {
    __shared__ float sw1[8 * 32], sb1[32], sw2[32 * 16], sb2[16], sw3[16 * 2], sb3[2];
    for (int t = threadIdx.x; t < 8 * 32; t += blockDim.x) sw1[t] = w1[t];
    for (int t = threadIdx.x; t < 32 * 16; t += blockDim.x) sw2[t] = w2[t];
    for (int t = threadIdx.x; t < 32; t += blockDim.x) sb1[t] = b1[t];
    for (int t = threadIdx.x; t < 16; t += blockDim.x) sb2[t] = b2[t];
    for (int t = threadIdx.x; t < 32; t += blockDim.x) {
        if (t < 16 * 2) sw3[t] = w3[t];
        if (t < 2) sb3[t] = b3[t];
    }
    __syncthreads();
    int i = blockIdx.x * blockDim.x + threadIdx.x;
    if (i >= n) return;

    float hv[8];
    #pragma unroll
    for (int f = 0; f < 8; ++f) hv[f] = h[(size_t)i * 8 + f];

    float a1[32];
    #pragma unroll
    for (int o = 0; o < 32; ++o) {
        float acc = sb1[o];
        #pragma unroll
        for (int f = 0; f < 8; ++f) acc += hv[f] * sw1[f * 32 + o];
        a1[o] = tanhf(acc);
    }
    float a2[16];
    #pragma unroll
    for (int o = 0; o < 16; ++o) {
        float acc = sb2[o];
        #pragma unroll
        for (int f = 0; f < 32; ++f) acc += a1[f] * sw2[f * 16 + o];
        a2[o] = tanhf(acc);
    }
    float o0 = sb3[0], o1 = sb3[1];
    #pragma unroll
    for (int f = 0; f < 16; ++f) {
        o0 += a2[f] * sw3[f * 2 + 0];
        o1 += a2[f] * sw3[f * 2 + 1];
    }
    float m = fmaxf(o0, o1);
    float e0 = expf(o0 - m), e1 = expf(o1 - m);
    float inv = 1.f / (e0 + e1);
    out[(size_t)i * 2 + 0] = e0 * inv;
    out[(size_t)i * 2 + 1] = e1 * inv;
}

// ---------------- launch ----------------
extern "C" void kernel_launch(void* const* d_in, const int* in_sizes, int n_in,
                              void* d_out, int out_size, void* d_ws, size_t ws_size,
                              hipStream_t stream) {
    const int N = in_sizes[0] / 3;
    const int E = in_sizes[1] / 2;

    const float* x = (const float*)d_in[0];
    const int* edge = (const int*)d_in[1];
    const int* e_src = edge;
    const int* e_dst = edge + E;

    const float* c_wl[7]; const float* c_bl[7]; const float* c_wr[7];
    for (int k = 0; k < 7; ++k) {
        c_wl[k] = (const float*)d_in[2 + 3 * k + 0];
        c_bl[k] = (const float*)d_in[2 + 3 * k + 1];
        c_wr[k] = (const float*)d_in[2 + 3 * k + 2];
    }
    const float* l1w = (const float*)d_in[23];
    const float* l1b = (const float*)d_in[24];
    const float* l2w = (const float*)d_in[25];
    const float* l2b = (const float*)d_in[26];
    const float* l3w = (const float*)d_in[27];
    const float* l3b = (const float*)d_in[28];
    float* out = (float*)d_out;

    char* ws = (char*)d_ws;
    size_t off = 0;
    auto alloc = [&](size_t bytes) -> char* {
        char* p = ws + off;
        off = (off + bytes + 255) & ~(size_t)255;
        return p;
    };
    float* part = (float*)alloc(11 * STAT_BLOCKS * sizeof(float));
    float* stats = (float*)alloc(16 * sizeof(float));
    float* h0 = (float*)alloc((size_t)N * 3 * sizeof(float));
    float* x1 = (float*)alloc((size_t)N * 8 * sizeof(float));
    float* x2 = (float*)alloc((size_t)N * 16 * sizeof(float));
    float* x3 = (float*)alloc((size_t)N * 32 * sizeof(float));
    float* x4 = (float*)alloc((size_t)N * 64 * sizeof(float));
    float* t5 = (float*)alloc((size_t)N * 32 * sizeof(float));
    float* t6 = (float*)alloc((size_t)N * 16 * sizeof(float));
    float* t7 = (float*)alloc((size_t)N * 8 * sizeof(float));
    float* M = (float*)alloc((size_t)N * 32 * sizeof(float));   // mean buffer / CSR part_hist
    int* deg = (int*)alloc((size_t)N * sizeof(int));
    int* row_ptr = (int*)alloc(((size_t)N + 1) * sizeof(int));
    int* bsum = (int*)alloc(1024 * sizeof(int));
    int* bscan = (int*)alloc(1024 * sizeof(int));
    int* csrmeta = (int*)alloc((2 * NCH * NR + 16) * sizeof(int));
    int* csr_src = (int*)alloc((size_t)E * sizeof(int));
    (void)ws_size;

    // CSR scratch aliases (all dead before the conv pipeline writes them):
    int* bdst = (int*)x4;                  // bucketed dst: E ints
    int* bsrc = (int*)x4 + E;              // bucketed src: E ints
    int* part_hist = (int*)M;              // NR*NSC*rn ints <= N*32 + 224
    int* counts = csrmeta;
    int* gof = csrmeta + NCH * NR;
    int* bb = csrmeta + 2 * NCH * NR;      // NR+1 bases

    // gather tables aliased into dead f32 regions (lifetimes verified):
    u16* xb1 = (u16*)t7;                 // bf16, live: after c1 .. agg_c2   (t7 written at dense_c3r)
    u16* xb2 = (u16*)t6;                 // bf16, live: dense_c2 .. agg_c3   (t6 written at dense_c2r)
    u32* xq3 = (u32*)t5;                 // fp8,  live: dense_c3 .. agg_c4   (t5 written at dense_c1r)
    u32* yq5 = (u32*)t6;                 // fp8,  live: premult_c1r .. agg_c1r (xb2 dead; t6 written at dense_c2r)
    u16* y6  = (u16*)x4;                 // bf16, live: premult_c2r .. agg_c2r (x4 dead after dense_c1r)
    u16* y7  = (u16*)x4 + (size_t)N * 16;// bf16, live: premult_c3r .. agg_c3r (disjoint from y6)

    const int BT = 256;
    const int nB_N = (N + BT - 1) / BT;

    stats_partial_kernel<<<STAT_BLOCKS, BT, 0, stream>>>(x, part, N);
    stats_final_kernel<<<1, 64, 0, stream>>>(part, stats, N);
    normalize_kernel<<<nB_N, BT, 0, stream>>>(x, stats, h0, N);

    // CSR build (radix partition + LDS histograms; no global atomics)
    const int rn = (N + NR - 1) / NR;
    const int ech = (E + NCH - 1) / NCH;
    cnt_kernel<<<NCH, BT, 0, stream>>>(e_dst, counts, E, ech, rn);
    boff_kernel<<<1, 64, 0, stream>>>(counts, gof, bb);
    scatter_kernel<<<NCH, BT, 0, stream>>>(e_src, e_dst, gof, bdst, bsrc, E, ech, rn);
    hist2_kernel<<<NR * NSC, BT, 0, stream>>>(bdst, bb, part_hist, rn, N);
    prefix2_kernel<<<nB_N, BT, 0, stream>>>(part_hist, deg, rn, N);
    const int nbScan = (N + SCAN_BS - 1) / SCAN_BS;
    scanA_kernel<<<nbScan, 256, 0, stream>>>(deg, bsum, N);
    scanB_kernel<<<1, 1024, 0, stream>>>(bsum, bscan, row_ptr + N, nbScan);
    scanC_kernel<<<nbScan, 256, 0, stream>>>(deg, bscan, row_ptr, N);
    fill2_kernel<<<NR * NSC, BT, 0, stream>>>(bdst, bsrc, bb, row_ptr, part_hist, csr_src, rn, N);

    const int WPB = 4;
    const int nB_W = (N + WPB - 1) / WPB;
    const int nB_W2 = (N + 2 * WPB - 1) / (2 * WPB);

    // c1: 3 -> 8 (fused wave-per-node, tiny)
    conv_small_kernel<3, 8, 4, false><<<nB_W, BT, 0, stream>>>(h0, c_wl[0], c_bl[0], c_wr[0], nullptr, x1, row_ptr, csr_src, N);
    cast_bf16_kernel<<<(N + BT - 1) / BT, BT, 0, stream>>>(x1, xb1, N);
    // c2: 8 -> 16 (agg2 bf16 + dense, emit bf16 table for c3)
    agg2_bf16_kernel<1><<<nB_W2, BT, 0, stream>>>(xb1, M, row_ptr, csr_src, N);
    dense_fwd_kernel<8, 16, 16, 1><<<dim3(nB_N, 1), BT, 0, stream>>>(M, x1, c_wl[1], c_bl[1], c_wr[1], x2, xb2, N);
    // c3: 16 -> 32 (agg bf16 + dense single-tile, emit fp8 table for c4)
    agg_bf16_kernel<16, 2><<<nB_W, BT, 0, stream>>>(xb2, M, row_ptr, csr_src, N);
    dense_fwd_kernel<16, 32, 32, 2><<<dim3(nB_N, 1), BT, 0, stream>>>(M, x2, c_wl[2], c_bl[2], c_wr[2], x3, xq3, N);
    // c4: 32 -> 64 (agg fp8 + dense single 64-wide tile)
    agg_fp8_kernel<32, 4><<<nB_W, BT, 0, stream>>>(xq3, M, row_ptr, csr_src, N);
    dense_fwd_kernel<32, 64, 64, 0><<<dim3(nB_N, 1), BT, 0, stream>>>(M, x3, c_wl[3], c_bl[3], c_wr[3], x4, nullptr, N);
    // c1r: 64 -> 32 (premult fp8 single-tile, agg fp8, dense rev single-tile + res x3)
    premult_fp8_kernel<64, 32, 32><<<dim3(nB_N, 1), BT, 0, stream>>>(x4, c_wl[4], yq5, N);
    agg_fp8_kernel<32, 4><<<nB_W, BT, 0, stream>>>(yq5, M, row_ptr, csr_src, N);
    dense_rev_kernel<64, 32, 32><<<dim3(nB_N, 1), BT, 0, stream>>>(M, x4, c_bl[4], c_wr[4], x3, t5, N);
    // c2r: 32 -> 16 (premult bf16, agg bf16, dense rev + res x2)
    premult_kernel<32, 16><<<nB_N, BT, 0, stream>>>(t5, c_wl[5], y6, N);
    agg_bf16_kernel<16, 2><<<nB_W, BT, 0, stream>>>(y6, M, row_ptr, csr_src, N);
    dense_rev_kernel<32, 16, 16><<<dim3(nB_N, 1), BT, 0, stream>>>(M, t5, c_bl[5], c_wr[5], x2, t6, N);
    // c3r: 16 -> 8 (premult bf16, agg2 bf16, dense rev + res x1)
    premult_kernel<16, 8><<<nB_N, BT, 0, stream>>>(t6, c_wl[6], y7, N);
    agg2_bf16_kernel<1><<<nB_W2, BT, 0, stream>>>(y7, M, row_ptr, csr_src, N);
    dense_rev_kernel<16, 8, 8><<<dim3(nB_N, 1), BT, 0, stream>>>(M, t6, c_bl[6], c_wr[6], x1, t7, N);

    mlp_kernel<<<nB_N, BT, 0, stream>>>(t7, l1w, l1b, l2w, l2b, l3w, l3b, out, N);
}